// Round 6
// baseline (330.509 us; speedup 1.0000x reference)
//
#include <hip/hip_runtime.h>
#include <hip/hip_cooperative_groups.h>

namespace cg = cooperative_groups;

// FlowLenia step, SX=SY=256, C=3, K=15 — single cooperative launch.
// Phases (grid.sync between):
//   P1 row-FFT of A (block=x, waves 0-2 = channels) -> RF [c][x][0..128] (136-padded)
//   P2 fwd col-FFT + fK mul + inv col-FFT per k     -> T2 [k][x][0..128] (hermitian)
//   P3 conj-mirror + inv row-FFT + growth*P + collapse -> Ucol (block=x, 15 k on 8 waves)
//   P4 fused Sobel flow + 5x5 reint + softmax mix   -> d_out (newA | newP)
//
// Round-5 change: the 4 dispatches are fused into one hipLaunchCooperativeKernel
// (grid=256 x 512, 1 block/CU co-resident: LDS 53.9KB <= 64KB). The FFT
// primitive is block-barrier-free (wave-private LDS + wave fences), so phases
// with partially-active waves are legal. Removes ~3 launch boundaries.

#define XY  65536
#define NC  3
#define NK  15
#define WPAD 260   // per-wave LDS buffer stride (float2)
#define RW  136    // padded row width (float2) for RF/T2: cols 0..128 valid

__device__ __forceinline__ float2 cmul(float2 a, float2 b) {
  return make_float2(a.x * b.x - a.y * b.y, a.x * b.y + a.y * b.x);
}

// Bank swizzle for the 256-element FFT buffers.
__device__ __forceinline__ int swz(int i) { return i ^ ((i >> 4) & 15); }

// Compiler-only fence: same-wave LDS ops execute in issue order, so for
// wave-private LDS reuse a scheduling fence suffices (no s_barrier).
__device__ __forceinline__ void wave_fence() {
  asm volatile("" ::: "memory");
  __builtin_amdgcn_wave_barrier();
  asm volatile("" ::: "memory");
}

// 256-pt Stockham radix-4 FFT on a wave-private 256-float2 LDS buffer pair.
// t = lane (0..63). sign = -1 fwd, +1 inv (unnormalized). Result lands in b0
// (under the swz() mapping). Wave-local: no block barriers.
__device__ __forceinline__ void fft256_wave(float2* b0, float2* b1, int t, float sign) {
  float2* src = b0;
  float2* dst = b1;
#pragma unroll
  for (int stage = 0; stage < 4; ++stage) {
    wave_fence();  // order vs caller's fill / previous stage's writes
    const int Ns = 1 << (2 * stage);
    float2 v0 = src[swz(t)];
    float2 v1 = src[swz(t + 64)];
    float2 v2 = src[swz(t + 128)];
    float2 v3 = src[swz(t + 192)];
    const int jm = t & (Ns - 1);
    float ang = sign * 6.283185307179586f * (float)jm / (float)(Ns * 4);
    float sn, cs;
    __sincosf(ang, &sn, &cs);
    float2 w1 = make_float2(cs, sn);
    float2 w2 = cmul(w1, w1);
    float2 w3 = cmul(w2, w1);
    v1 = cmul(v1, w1);
    v2 = cmul(v2, w2);
    v3 = cmul(v3, w3);
    float2 a0 = make_float2(v0.x + v2.x, v0.y + v2.y);
    float2 a1 = make_float2(v0.x - v2.x, v0.y - v2.y);
    float2 a2 = make_float2(v1.x + v3.x, v1.y + v3.y);
    float2 a3 = make_float2(v1.x - v3.x, v1.y - v3.y);
    float2 ia3 = make_float2(-sign * a3.y, sign * a3.x);  // (sign*i)*a3
    const int idxD = ((t >> (2 * stage)) << (2 * stage)) * 4 + jm;  // (t/Ns)*4Ns + jm
    dst[swz(idxD)]          = make_float2(a0.x + a2.x, a0.y + a2.y);
    dst[swz(idxD + Ns)]     = make_float2(a1.x + ia3.x, a1.y + ia3.y);
    dst[swz(idxD + 2 * Ns)] = make_float2(a0.x - a2.x, a0.y - a2.y);
    dst[swz(idxD + 3 * Ns)] = make_float2(a1.x - ia3.x, a1.y - ia3.y);
    float2* tmp = src; src = dst; dst = tmp;
  }
  wave_fence();  // make final writes safe to read (same wave)
}

__global__ __launch_bounds__(512, 1) void k_mega(const float* __restrict__ A,
                                                 const float* __restrict__ P,
                                                 const float* __restrict__ fKr,
                                                 const float* __restrict__ fKi,
                                                 const float* __restrict__ m,
                                                 const float* __restrict__ s,
                                                 float2* __restrict__ RF,
                                                 float2* __restrict__ T2,
                                                 float* __restrict__ Ucol,
                                                 float* __restrict__ outA,
                                                 float* __restrict__ outP) {
  __shared__ union {
    struct { float2 l0[8 * WPAD], l1[8 * WPAD]; } fft;                       // P1, P2: 33.3KB
    struct { float2 l0[8 * WPAD], l1[8 * WPAD]; float accs[15 * WPAD]; } p3; // P3: 48.9KB
    struct { float4 lAF[484], lU[484], lF[2 * 400], lP[4 * 400]; } p4;       // P4: 53.9KB
  } sm;
  cg::grid_group grid = cg::this_grid();
  const int tid = threadIdx.x;
  const int bid = blockIdx.x;   // grid = 256
  const int w = tid >> 6, lane = tid & 63;

  // ===== Phase 1: forward row FFT of A. block = x, wave w<3 = channel. =====
  if (w < 3) {
    const int c = w;
    const int x = bid;
    float2* b0 = sm.fft.l0 + w * WPAD;
    float2* b1 = sm.fft.l1 + w * WPAD;
#pragma unroll
    for (int r = 0; r < 4; ++r) {
      int y = lane + 64 * r;
      b0[swz(y)] = make_float2(A[(x * 256 + y) * NC + c], 0.0f);
    }
    fft256_wave(b0, b1, lane, -1.0f);
    float2* dst = RF + (c * 256 + x) * RW;
#pragma unroll
    for (int r = 0; r < 2; ++r) {
      int y = lane + 64 * r;
      dst[y] = b0[swz(y)];
    }
    if (lane < 8) {
      dst[128 + lane] = (lane == 0) ? b0[swz(128)] : make_float2(0.f, 0.f);
    }
  }
  __threadfence();
  grid.sync();

  // ===== Phase 2: col FFT + fK mul + inv col FFT. 255 jobs (k, tile). =====
  if (bid < 255) {
    const int k = bid / 17;
    const int tile = bid - k * 17;
    const int y0 = (tile < 16) ? (tile << 3) : 128;
    const int c = k % 3;
    const int y = y0 + w;

    // Prefetch the fK gather so its latency hides under the forward FFT.
    float2 Kv[4];
#pragma unroll
    for (int r = 0; r < 4; ++r) {
      const int xx = lane + 64 * r;
      const int fi = (xx * 256 + y) * NK + k;
      Kv[r] = make_float2(fKr[fi], fKi[fi]);
    }

    // Tile load: chunk q (16B) of row x holds columns y0+2q, y0+2q+1.
    {
      const int q = tid & 3;
#pragma unroll
      for (int r = 0; r < 2; ++r) {
        const int x = (tid >> 2) + (r << 7);
        const float4* src = (const float4*)(RF + (c * 256 + x) * RW + y0);
        float4 v = src[q];
        sm.fft.l0[(2 * q) * WPAD + swz(x)]     = make_float2(v.x, v.y);
        sm.fft.l0[(2 * q + 1) * WPAD + swz(x)] = make_float2(v.z, v.w);
      }
    }
    __syncthreads();  // cross-wave: tile fill -> wave-private FFT reads

    float2* b0 = sm.fft.l0 + w * WPAD;
    float2* b1 = sm.fft.l1 + w * WPAD;
    fft256_wave(b0, b1, lane, -1.0f);

    float2 fa[4];
#pragma unroll
    for (int r = 0; r < 4; ++r) fa[r] = b0[swz(lane + 64 * r)];
#pragma unroll
    for (int r = 0; r < 4; ++r) {
      const int x = lane + 64 * r;
      b0[swz(x)] = cmul(Kv[r], fa[r]);
    }
    fft256_wave(b0, b1, lane, 1.0f);
    __syncthreads();  // cross-wave: FFT results -> cooperative tile store

    // Tile store: mirror of the load.
    {
      const int q = tid & 3;
#pragma unroll
      for (int r = 0; r < 2; ++r) {
        const int x = (tid >> 2) + (r << 7);
        float2 v0 = sm.fft.l0[(2 * q) * WPAD + swz(x)];
        float2 v1 = sm.fft.l0[(2 * q + 1) * WPAD + swz(x)];
        float4* dst = (float4*)(T2 + (k * 256 + x) * RW + y0);
        dst[q] = make_float4(v0.x, v0.y, v1.x, v1.y);
      }
    }
  }
  __threadfence();
  grid.sync();

  // ===== Phase 3: conj-mirror + inv row FFT + growth*P + collapse. =====
  // block = x; wave w handles k = w, w+8 (15 FFTs on 8 waves).
  {
    const int x = bid;
    float2* b0 = sm.p3.l0 + w * WPAD;
    float2* b1 = sm.p3.l1 + w * WPAD;
    for (int k = w; k < NK; k += 8) {
      float pv[4];
#pragma unroll
      for (int r = 0; r < 4; ++r) {
        int y = lane + 64 * r;
        pv[r] = P[(x * 256 + y) * NK + k];
      }
      const float mk = m[k];
      const float sk = s[k];
      const float inv2s2 = 0.5f / (sk * sk);

      const float2* src = T2 + (k * 256 + x) * RW;
#pragma unroll
      for (int r = 0; r < 2; ++r) {
        int y = lane + 64 * r;
        float2 v = src[y];
        b0[swz(y)] = v;
        if (y > 0) b0[swz(256 - y)] = make_float2(v.x, -v.y);  // conj mirror
      }
      if (lane == 0) b0[swz(128)] = src[128];
      fft256_wave(b0, b1, lane, 1.0f);

#pragma unroll
      for (int r = 0; r < 4; ++r) {
        int y = lane + 64 * r;
        float U = b0[swz(y)].x * (1.0f / 65536.0f);
        float d = U - mk;
        float g = 2.0f * __expf(-d * d * inv2s2) - 1.0f;
        sm.p3.accs[k * WPAD + y] = g * pv[r];
      }
    }
    __syncthreads();  // cross-wave: accs -> collapse
    if (tid < 256) {
#pragma unroll
      for (int c = 0; c < NC; ++c) {
        float sum = 0.f;
#pragma unroll
        for (int j2 = 0; j2 < 5; ++j2) sum += sm.p3.accs[(c + 3 * j2) * WPAD + tid];
        Ucol[c * XY + x * 256 + tid] = sum;
      }
    }
  }
  __threadfence();
  grid.sync();

  // ===== Phase 4: fused Sobel flow + tiled reintegration. block = 16x16 tile. =====
  {
    const int x0 = (bid >> 4) << 4;
    const int y0t = (bid & 15) << 4;
    const float MA = 4.35f;
    const float SIGMA = 0.65f;
    const float INV4S2 = 1.0f / (4.0f * 0.65f * 0.65f);
    const float DT = 0.2f;

    // --- staging: 22x22 halo of {A, Asum, Ucol}; 20x20 halo of P.
    for (int cell = tid; cell < 484; cell += 512) {
      const int r = cell / 22, cc = cell - r * 22;
      const int sx = (x0 + r - 3) & 255;
      const int sy = (y0t + cc - 3) & 255;
      const int sb = sx * 256 + sy;
      const float* ap = A + sb * NC;
      const float a0 = ap[0], a1 = ap[1], a2 = ap[2];
      sm.p4.lAF[cell] = make_float4(a0, a1, a2, a0 + a1 + a2);
      sm.p4.lU[cell] = make_float4(Ucol[sb], Ucol[XY + sb], Ucol[2 * XY + sb], 0.f);
    }
    for (int cell = tid; cell < 400; cell += 512) {
      const int r = cell / 20, cc = cell - r * 20;
      const int sx = (x0 + r - 2) & 255;
      const int sy = (y0t + cc - 2) & 255;
      const float* pp = P + (sx * 256 + sy) * NK;
      sm.p4.lP[0 * 400 + cell] = make_float4(pp[0], pp[1], pp[2], pp[3]);
      sm.p4.lP[1 * 400 + cell] = make_float4(pp[4], pp[5], pp[6], pp[7]);
      sm.p4.lP[2 * 400 + cell] = make_float4(pp[8], pp[9], pp[10], pp[11]);
      sm.p4.lP[3 * 400 + cell] = make_float4(pp[12], pp[13], pp[14], 0.f);
    }
    __syncthreads();

    // --- F on the 20x20 halo, from LDS (zero-masked at the true border).
    for (int cell = tid; cell < 400; cell += 512) {
      const int fr = cell / 20, fc = cell - fr * 20;
      const int sx = (x0 + fr - 2) & 255;
      const int sy = (y0t + fc - 2) & 255;
      float u[3][3][3];
      float as[3][3];
#pragma unroll
      for (int di = -1; di <= 1; ++di) {
#pragma unroll
        for (int dj = -1; dj <= 1; ++dj) {
          const bool zb = (sx == 0 && di < 0) || (sx == 255 && di > 0) ||
                          (sy == 0 && dj < 0) || (sy == 255 && dj > 0);
          float4 uv = make_float4(0.f, 0.f, 0.f, 0.f);
          float av = 0.f;
          if (!zb) {
            const int lc = (fr + 1 + di) * 22 + (fc + 1 + dj);
            uv = sm.p4.lU[lc];
            av = sm.p4.lAF[lc].w;
          }
          u[0][di + 1][dj + 1] = uv.x;
          u[1][di + 1][dj + 1] = uv.y;
          u[2][di + 1][dj + 1] = uv.z;
          as[di + 1][dj + 1] = av;
        }
      }
      const float cg0 = (as[2][0] + 2.f * as[2][1] + as[2][2]) -
                        (as[0][0] + 2.f * as[0][1] + as[0][2]);
      const float cg1 = (as[0][2] + 2.f * as[1][2] + as[2][2]) -
                        (as[0][0] + 2.f * as[1][0] + as[2][0]);
      const float4 ac = sm.p4.lAF[(fr + 1) * 22 + (fc + 1)];
      float fo[2][3];
#pragma unroll
      for (int c = 0; c < NC; ++c) {
        float f0 = (u[c][2][0] + 2.f * u[c][2][1] + u[c][2][2]) -
                   (u[c][0][0] + 2.f * u[c][0][1] + u[c][0][2]);
        float f1 = (u[c][0][2] + 2.f * u[c][1][2] + u[c][2][2]) -
                   (u[c][0][0] + 2.f * u[c][1][0] + u[c][2][0]);
        const float a = (c == 0) ? ac.x : (c == 1) ? ac.y : ac.z;
        const float ah = a * 0.5f;
        const float al = fminf(ah * ah, 1.0f);
        fo[0][c] = fminf(fmaxf(f0 * (1.f - al) - cg0 * al, -MA), MA);
        fo[1][c] = fminf(fmaxf(f1 * (1.f - al) - cg1 * al, -MA), MA);
      }
      sm.p4.lF[0 * 400 + cell] = make_float4(fo[0][0], fo[0][1], fo[0][2], fo[1][0]);
      sm.p4.lF[1 * 400 + cell] = make_float4(fo[1][1], fo[1][2], 0.f, 0.f);
    }
    __syncthreads();

    // --- reintegration from LDS (1 thread/pixel, tid < 256).
    if (tid < 256) {
      const int lx = tid >> 4, ly = tid & 15;
      const int x = x0 + lx, y = y0t + ly;
      const float px = x + 0.5f;
      const float py = y + 0.5f;

      float accA0 = 0.f, accA1 = 0.f, accA2 = 0.f;
      float accP[15];
#pragma unroll
      for (int k = 0; k < NK; ++k) accP[k] = 0.f;
      float esum = 0.f;

#pragma unroll
      for (int dx = -2; dx <= 2; ++dx) {
#pragma unroll
        for (int dy = -2; dy <= 2; ++dy) {
          const int lc = (lx + 2 - dx) * 20 + (ly + 2 - dy);       // 20x20 coords
          const int la = (lx + 3 - dx) * 22 + (ly + 3 - dy);       // 22x22 coords
          const int sx = (x - dx) & 255;
          const int sy = (y - dy) & 255;
          const float spx = sx + 0.5f;
          const float spy = sy + 0.5f;
          const float4 av = sm.p4.lAF[la];
          const float4 fv0 = sm.p4.lF[0 * 400 + lc];
          const float4 fv1 = sm.p4.lF[1 * 400 + lc];
          // c = 0
          float mu0 = fminf(fmaxf(spx + DT * fv0.x, SIGMA), 256.f - SIGMA);
          float mu1 = fminf(fmaxf(spy + DT * fv0.w, SIGMA), 256.f - SIGMA);
          float sz0 = fminf(fmaxf(0.5f - fabsf(px - mu0) + SIGMA, 0.f), 1.f);
          float sz1 = fminf(fmaxf(0.5f - fabsf(py - mu1) + SIGMA, 0.f), 1.f);
          float na0 = av.x * (sz0 * sz1 * INV4S2);
          // c = 1
          mu0 = fminf(fmaxf(spx + DT * fv0.y, SIGMA), 256.f - SIGMA);
          mu1 = fminf(fmaxf(spy + DT * fv1.x, SIGMA), 256.f - SIGMA);
          sz0 = fminf(fmaxf(0.5f - fabsf(px - mu0) + SIGMA, 0.f), 1.f);
          sz1 = fminf(fmaxf(0.5f - fabsf(py - mu1) + SIGMA, 0.f), 1.f);
          float na1 = av.y * (sz0 * sz1 * INV4S2);
          // c = 2
          mu0 = fminf(fmaxf(spx + DT * fv0.z, SIGMA), 256.f - SIGMA);
          mu1 = fminf(fmaxf(spy + DT * fv1.y, SIGMA), 256.f - SIGMA);
          sz0 = fminf(fmaxf(0.5f - fabsf(px - mu0) + SIGMA, 0.f), 1.f);
          sz1 = fminf(fmaxf(0.5f - fabsf(py - mu1) + SIGMA, 0.f), 1.f);
          float na2 = av.z * (sz0 * sz1 * INV4S2);

          const float e = __expf(na0 + na1 + na2) - 1.0f;
          accA0 += na0; accA1 += na1; accA2 += na2;
          esum += e;
          const float4 p0 = sm.p4.lP[0 * 400 + lc];
          const float4 p1 = sm.p4.lP[1 * 400 + lc];
          const float4 p2 = sm.p4.lP[2 * 400 + lc];
          const float4 p3 = sm.p4.lP[3 * 400 + lc];
          accP[0]  += p0.x * e; accP[1]  += p0.y * e; accP[2]  += p0.z * e; accP[3]  += p0.w * e;
          accP[4]  += p1.x * e; accP[5]  += p1.y * e; accP[6]  += p1.z * e; accP[7]  += p1.w * e;
          accP[8]  += p2.x * e; accP[9]  += p2.y * e; accP[10] += p2.z * e; accP[11] += p2.w * e;
          accP[12] += p3.x * e; accP[13] += p3.y * e; accP[14] += p3.z * e;
        }
      }

      const int b = x * 256 + y;
      outA[b * NC + 0] = accA0;
      outA[b * NC + 1] = accA1;
      outA[b * NC + 2] = accA2;
      const float inv = 1.0f / (esum + 1e-10f);
#pragma unroll
      for (int k = 0; k < NK; ++k) outP[b * NK + k] = accP[k] * inv;
    }
  }
}

extern "C" void kernel_launch(void* const* d_in, const int* in_sizes, int n_in,
                              void* d_out, int out_size, void* d_ws, size_t ws_size,
                              hipStream_t stream) {
  const float* A   = (const float*)d_in[0];
  const float* P   = (const float*)d_in[1];
  const float* fKr = (const float*)d_in[2];
  const float* fKi = (const float*)d_in[3];
  const float* m   = (const float*)d_in[4];
  const float* s   = (const float*)d_in[5];

  float* ws = (float*)d_ws;
  float2* RF   = (float2*)ws;                  // 3 * 256 * 136 complex
  float2* T2   = RF + NC * 256 * RW;           // 15 * 256 * 136 complex
  float*  Ucol = (float*)(T2 + NK * 256 * RW); // 3 * 65536 float

  float* outA = (float*)d_out;
  float* outP = outA + NC * XY;

  void* args[] = {(void*)&A, (void*)&P, (void*)&fKr, (void*)&fKi, (void*)&m,
                  (void*)&s, (void*)&RF, (void*)&T2, (void*)&Ucol,
                  (void*)&outA, (void*)&outP};
  hipLaunchCooperativeKernel((void*)k_mega, dim3(256), dim3(512), args, 0, stream);
}

// Round 7
// 99.190 us; speedup vs baseline: 3.3321x; 3.3321x over previous
//
#include <hip/hip_runtime.h>

// FlowLenia step, SX=SY=256, C=3, K=15.
// Pipeline (4 kernels) — REVERT to the round-4 best (100.1 us):
//   K1 row-FFT of A (3 planes, 4 waves/block)       -> RF [c][x][0..128] complex (136-padded)
//   K2 fwd col-FFT + fK mul + inv col-FFT per k     -> T2 [k][x][0..128] complex (hermitian)
//   K3 conj-mirror + inv row-FFT + growth*P + collapse -> Ucol [c][x][y] real
//   K45 fused Sobel flow + 5x5 reint + softmax mix  -> d_out (newA | newP)
//
// Round-5 post-mortem: single cooperative launch with 3x grid.sync() cost
// ~80 us PER SYNC on gfx950 (k_mega 250 us, VALUBusy 2.4% -> pure stall);
// kernel-boundary sync (~2 us) is 40x cheaper. Cooperative fusion is a
// dead end here; the 4-launch structure is the practical floor:
// ~84 us harness poison fills (untouchable) + ~16 us pipeline.

#define XY  65536
#define NC  3
#define NK  15
#define WPAD 260   // per-wave LDS buffer stride (float2)
#define RW  136    // padded row width (float2) for RF/T2: cols 0..128 valid

__device__ __forceinline__ float2 cmul(float2 a, float2 b) {
  return make_float2(a.x * b.x - a.y * b.y, a.x * b.y + a.y * b.x);
}

// Bank swizzle for the 256-element FFT buffers.
__device__ __forceinline__ int swz(int i) { return i ^ ((i >> 4) & 15); }

// Compiler-only fence: same-wave LDS ops execute in issue order, so for
// wave-private LDS reuse a scheduling fence suffices (no s_barrier).
__device__ __forceinline__ void wave_fence() {
  asm volatile("" ::: "memory");
  __builtin_amdgcn_wave_barrier();
  asm volatile("" ::: "memory");
}

// 256-pt Stockham radix-4 FFT on a wave-private 256-float2 LDS buffer pair.
// t = lane (0..63). sign = -1 fwd, +1 inv (unnormalized). Result lands in b0
// (under the swz() mapping). Wave-local: callers __syncthreads() around any
// cross-wave fill/consume and address elements through swz().
__device__ __forceinline__ void fft256_wave(float2* b0, float2* b1, int t, float sign) {
  float2* src = b0;
  float2* dst = b1;
#pragma unroll
  for (int stage = 0; stage < 4; ++stage) {
    wave_fence();  // order vs caller's fill / previous stage's writes
    const int Ns = 1 << (2 * stage);
    float2 v0 = src[swz(t)];
    float2 v1 = src[swz(t + 64)];
    float2 v2 = src[swz(t + 128)];
    float2 v3 = src[swz(t + 192)];
    const int jm = t & (Ns - 1);
    float ang = sign * 6.283185307179586f * (float)jm / (float)(Ns * 4);
    float sn, cs;
    __sincosf(ang, &sn, &cs);
    float2 w1 = make_float2(cs, sn);
    float2 w2 = cmul(w1, w1);
    float2 w3 = cmul(w2, w1);
    v1 = cmul(v1, w1);
    v2 = cmul(v2, w2);
    v3 = cmul(v3, w3);
    float2 a0 = make_float2(v0.x + v2.x, v0.y + v2.y);
    float2 a1 = make_float2(v0.x - v2.x, v0.y - v2.y);
    float2 a2 = make_float2(v1.x + v3.x, v1.y + v3.y);
    float2 a3 = make_float2(v1.x - v3.x, v1.y - v3.y);
    float2 ia3 = make_float2(-sign * a3.y, sign * a3.x);  // (sign*i)*a3
    const int idxD = ((t >> (2 * stage)) << (2 * stage)) * 4 + jm;  // (t/Ns)*4Ns + jm
    dst[swz(idxD)]          = make_float2(a0.x + a2.x, a0.y + a2.y);
    dst[swz(idxD + Ns)]     = make_float2(a1.x + ia3.x, a1.y + ia3.y);
    dst[swz(idxD + 2 * Ns)] = make_float2(a0.x - a2.x, a0.y - a2.y);
    dst[swz(idxD + 3 * Ns)] = make_float2(a1.x - ia3.x, a1.y - ia3.y);
    float2* tmp = src; src = dst; dst = tmp;
  }
  wave_fence();  // make final writes safe to read (same wave)
}

// K1: forward FFT along y. 4 waves/block, wave w owns row x = 4*bid + w.
// grid = 3*64 blocks x 256. Stores only ky = 0..128 (+ zero pad to 135).
__global__ __launch_bounds__(256) void k_rowfft(const float* __restrict__ A,
                                                float2* __restrict__ RF) {
  __shared__ float2 l0[4 * WPAD], l1[4 * WPAD];
  const int tid = threadIdx.x;
  const int w = tid >> 6, lane = tid & 63;
  const int c = blockIdx.x >> 6;
  const int x = ((blockIdx.x & 63) << 2) + w;
  float2* b0 = l0 + w * WPAD;
  float2* b1 = l1 + w * WPAD;
#pragma unroll
  for (int r = 0; r < 4; ++r) {
    int y = lane + 64 * r;
    b0[swz(y)] = make_float2(A[(x * 256 + y) * NC + c], 0.0f);
  }
  fft256_wave(b0, b1, lane, -1.0f);
  float2* dst = RF + (c * 256 + x) * RW;
#pragma unroll
  for (int r = 0; r < 2; ++r) {
    int y = lane + 64 * r;
    dst[y] = b0[swz(y)];
  }
  if (lane < 8) {
    // y = 128 is the Nyquist column; 129..135 zero-padded.
    dst[128 + lane] = (lane == 0) ? b0[swz(128)] : make_float2(0.f, 0.f);
  }
}

// K2: per (k, 8-column tile): fwd col FFT, fK multiply, inverse col FFT.
// Hermitian: only ky = 0..128. 17 tiles: y0 in {0,8,...,120,128}; the last
// tile's columns 129..135 are zeros (from K1) and its stores are harmless.
// grid = 15*17 = 255 blocks x 512 (8 waves; wave w owns column y0+w).
__global__ __launch_bounds__(512, 1) void k_colfft(const float* __restrict__ fKr,
                                                   const float* __restrict__ fKi,
                                                   const float2* __restrict__ RF,
                                                   float2* __restrict__ T2) {
  __shared__ float2 lds0[8 * WPAD];
  __shared__ float2 lds1[8 * WPAD];
  const int tid = threadIdx.x;
  const int k = blockIdx.x / 17;
  const int tile = blockIdx.x - k * 17;
  const int y0 = (tile < 16) ? (tile << 3) : 128;
  const int c = k % 3;
  const int w = tid >> 6, lane = tid & 63;
  const int y = y0 + w;

  // Prefetch the fK gather so its latency hides under the forward FFT.
  // (y <= 135 < 256: always in-bounds of the full fK arrays; values for
  //  y > 128 multiply zero columns and are never consumed.)
  float2 Kv[4];
#pragma unroll
  for (int r = 0; r < 4; ++r) {
    const int xx = lane + 64 * r;
    const int fi = (xx * 256 + y) * NK + k;
    Kv[r] = make_float2(fKr[fi], fKi[fi]);
  }

  // Tile load: chunk q (16B) of row x holds columns y0+2q, y0+2q+1.
  // (c*256+x)*RW and y0 are even -> float4-aligned.
  {
    const int q = tid & 3;
#pragma unroll
    for (int r = 0; r < 2; ++r) {
      const int x = (tid >> 2) + (r << 7);
      const float4* src = (const float4*)(RF + (c * 256 + x) * RW + y0);
      float4 v = src[q];
      lds0[(2 * q) * WPAD + swz(x)]     = make_float2(v.x, v.y);
      lds0[(2 * q + 1) * WPAD + swz(x)] = make_float2(v.z, v.w);
    }
  }
  __syncthreads();  // cross-wave: tile fill -> wave-private FFT reads

  float2* b0 = lds0 + w * WPAD;
  float2* b1 = lds1 + w * WPAD;
  fft256_wave(b0, b1, lane, -1.0f);

  float2 fa[4];
#pragma unroll
  for (int r = 0; r < 4; ++r) fa[r] = b0[swz(lane + 64 * r)];
#pragma unroll
  for (int r = 0; r < 4; ++r) {
    const int x = lane + 64 * r;
    b0[swz(x)] = cmul(Kv[r], fa[r]);
  }
  fft256_wave(b0, b1, lane, 1.0f);
  __syncthreads();  // cross-wave: FFT results -> cooperative tile store

  // Tile store: mirror of the load.
  {
    const int q = tid & 3;
#pragma unroll
    for (int r = 0; r < 2; ++r) {
      const int x = (tid >> 2) + (r << 7);
      float2 v0 = lds0[(2 * q) * WPAD + swz(x)];
      float2 v1 = lds0[(2 * q + 1) * WPAD + swz(x)];
      float4* dst = (float4*)(T2 + (k * 256 + x) * RW + y0);
      dst[q] = make_float4(v0.x, v0.y, v1.x, v1.y);
    }
  }
}

// K3: per (c, x): 5 waves, wave j handles k=c+3j: load ky=0..128 from T2,
// conjugate-mirror to ky=129..255 (H[x][256-ky] = conj(H[x][ky])), inverse
// row FFT, growth*P, cross-wave collapse -> Ucol. grid = 3*256 blocks x 320.
__global__ __launch_bounds__(320, 1) void k_irowfft_growth(const float2* __restrict__ T2,
                                                           const float* __restrict__ P,
                                                           const float* __restrict__ m,
                                                           const float* __restrict__ s,
                                                           float* __restrict__ Ucol) {
  __shared__ float2 lds0[5 * WPAD];
  __shared__ float2 lds1[5 * WPAD];
  __shared__ float accs[5 * WPAD];
  const int tid = threadIdx.x;
  const int x = blockIdx.x & 255;
  const int c = blockIdx.x >> 8;
  const int j = tid >> 6, lane = tid & 63;
  const int k = c + 3 * j;

  // Prefetch the strided P gather; consumed after the FFT.
  float pv[4];
#pragma unroll
  for (int r = 0; r < 4; ++r) {
    int y = lane + 64 * r;
    pv[r] = P[(x * 256 + y) * NK + k];
  }
  const float mk = m[k];
  const float sk = s[k];
  const float inv2s2 = 0.5f / (sk * sk);

  float2* b0 = lds0 + j * WPAD;
  float2* b1 = lds1 + j * WPAD;
  const float2* src = T2 + (k * 256 + x) * RW;
#pragma unroll
  for (int r = 0; r < 2; ++r) {
    int y = lane + 64 * r;
    float2 v = src[y];
    b0[swz(y)] = v;
    if (y > 0) b0[swz(256 - y)] = make_float2(v.x, -v.y);  // conj mirror
  }
  if (lane == 0) b0[swz(128)] = src[128];
  fft256_wave(b0, b1, lane, 1.0f);

#pragma unroll
  for (int r = 0; r < 4; ++r) {
    int y = lane + 64 * r;
    float U = b0[swz(y)].x * (1.0f / 65536.0f);
    float d = U - mk;
    float g = 2.0f * __expf(-d * d * inv2s2) - 1.0f;
    accs[j * WPAD + y] = g * pv[r];
  }
  __syncthreads();  // cross-wave: accs -> collapse
  if (tid < 256) {
    float sum = 0.f;
#pragma unroll
    for (int j2 = 0; j2 < 5; ++j2) sum += accs[j2 * WPAD + tid];
    Ucol[c * XY + x * 256 + tid] = sum;
  }
}

// K45: fused Sobel flow + tiled reintegration.
// Each block owns a 16x16 pixel tile.
//   Phase 1: stage 22x22 halo of {A, Asum} and Ucol; 20x20 halo of P.
//   Phase 2: compute F on the 20x20 halo entirely from LDS (zero-masked at
//            the true image border, matching conv 'SAME' semantics).
//   Phase 3: 25-cell reintegration from LDS (exact: |DT*F| <= 0.87, box
//            halfwidth 1.15 -> |shift| >= 3 has area 0).
// grid = 256 blocks x 256.
__global__ __launch_bounds__(256) void k_flow_reint(const float* __restrict__ A,
                                                    const float* __restrict__ P,
                                                    const float* __restrict__ Ucol,
                                                    float* __restrict__ outA,
                                                    float* __restrict__ outP) {
  __shared__ float4 lAF[484];     // 22x22 {a0,a1,a2,asum} at global (x0+r-3, y0+c-3)
  __shared__ float4 lU[484];      // 22x22 {u0,u1,u2,-}
  __shared__ float4 lF[2][400];   // 20x20 [0]={f00,f01,f02,f10} [1]={f11,f12,-,-}
  __shared__ float4 lP[4][400];   // 20x20 k=4j..4j+3 (k=15 pad)
  const int tid = threadIdx.x;
  const int x0 = (blockIdx.x >> 4) << 4;
  const int y0 = (blockIdx.x & 15) << 4;
  const float MA = 4.35f;
  const float SIGMA = 0.65f;
  const float INV4S2 = 1.0f / (4.0f * 0.65f * 0.65f);
  const float DT = 0.2f;

  // --- Phase 1: staging.
  for (int cell = tid; cell < 484; cell += 256) {
    const int r = cell / 22, cc = cell - r * 22;
    const int sx = (x0 + r - 3) & 255;
    const int sy = (y0 + cc - 3) & 255;
    const int sb = sx * 256 + sy;
    const float* ap = A + sb * NC;
    const float a0 = ap[0], a1 = ap[1], a2 = ap[2];
    lAF[cell] = make_float4(a0, a1, a2, a0 + a1 + a2);
    lU[cell] = make_float4(Ucol[sb], Ucol[XY + sb], Ucol[2 * XY + sb], 0.f);
  }
  for (int cell = tid; cell < 400; cell += 256) {
    const int r = cell / 20, cc = cell - r * 20;
    const int sx = (x0 + r - 2) & 255;
    const int sy = (y0 + cc - 2) & 255;
    const float* pp = P + (sx * 256 + sy) * NK;
    lP[0][cell] = make_float4(pp[0], pp[1], pp[2], pp[3]);
    lP[1][cell] = make_float4(pp[4], pp[5], pp[6], pp[7]);
    lP[2][cell] = make_float4(pp[8], pp[9], pp[10], pp[11]);
    lP[3][cell] = make_float4(pp[12], pp[13], pp[14], 0.f);
  }
  __syncthreads();

  // --- Phase 2: F on the 20x20 halo, from LDS.
  for (int cell = tid; cell < 400; cell += 256) {
    const int fr = cell / 20, fc = cell - fr * 20;
    const int sx = (x0 + fr - 2) & 255;
    const int sy = (y0 + fc - 2) & 255;
    float u[3][3][3];
    float as[3][3];
#pragma unroll
    for (int di = -1; di <= 1; ++di) {
#pragma unroll
      for (int dj = -1; dj <= 1; ++dj) {
        const bool zb = (sx == 0 && di < 0) || (sx == 255 && di > 0) ||
                        (sy == 0 && dj < 0) || (sy == 255 && dj > 0);
        float4 uv = make_float4(0.f, 0.f, 0.f, 0.f);
        float av = 0.f;
        if (!zb) {
          const int lc = (fr + 1 + di) * 22 + (fc + 1 + dj);
          uv = lU[lc];
          av = lAF[lc].w;
        }
        u[0][di + 1][dj + 1] = uv.x;
        u[1][di + 1][dj + 1] = uv.y;
        u[2][di + 1][dj + 1] = uv.z;
        as[di + 1][dj + 1] = av;
      }
    }
    const float cg0 = (as[2][0] + 2.f * as[2][1] + as[2][2]) -
                      (as[0][0] + 2.f * as[0][1] + as[0][2]);
    const float cg1 = (as[0][2] + 2.f * as[1][2] + as[2][2]) -
                      (as[0][0] + 2.f * as[1][0] + as[2][0]);
    const float4 ac = lAF[(fr + 1) * 22 + (fc + 1)];
    float fo[2][3];
#pragma unroll
    for (int c = 0; c < NC; ++c) {
      float f0 = (u[c][2][0] + 2.f * u[c][2][1] + u[c][2][2]) -
                 (u[c][0][0] + 2.f * u[c][0][1] + u[c][0][2]);
      float f1 = (u[c][0][2] + 2.f * u[c][1][2] + u[c][2][2]) -
                 (u[c][0][0] + 2.f * u[c][1][0] + u[c][2][0]);
      const float a = (c == 0) ? ac.x : (c == 1) ? ac.y : ac.z;
      const float ah = a * 0.5f;
      const float al = fminf(ah * ah, 1.0f);
      fo[0][c] = fminf(fmaxf(f0 * (1.f - al) - cg0 * al, -MA), MA);
      fo[1][c] = fminf(fmaxf(f1 * (1.f - al) - cg1 * al, -MA), MA);
    }
    lF[0][cell] = make_float4(fo[0][0], fo[0][1], fo[0][2], fo[1][0]);
    lF[1][cell] = make_float4(fo[1][1], fo[1][2], 0.f, 0.f);
  }
  __syncthreads();

  // --- Phase 3: reintegration from LDS.
  const int lx = tid >> 4, ly = tid & 15;
  const int x = x0 + lx, y = y0 + ly;
  const float px = x + 0.5f;
  const float py = y + 0.5f;

  float accA0 = 0.f, accA1 = 0.f, accA2 = 0.f;
  float accP[15];
#pragma unroll
  for (int k = 0; k < NK; ++k) accP[k] = 0.f;
  float esum = 0.f;

#pragma unroll
  for (int dx = -2; dx <= 2; ++dx) {
#pragma unroll
    for (int dy = -2; dy <= 2; ++dy) {
      const int lc = (lx + 2 - dx) * 20 + (ly + 2 - dy);       // 20x20 coords
      const int la = (lx + 3 - dx) * 22 + (ly + 3 - dy);       // 22x22 coords
      const int sx = (x - dx) & 255;
      const int sy = (y - dy) & 255;
      const float spx = sx + 0.5f;
      const float spy = sy + 0.5f;
      const float4 av = lAF[la];
      const float4 fv0 = lF[0][lc];
      const float4 fv1 = lF[1][lc];
      // c = 0
      float mu0 = fminf(fmaxf(spx + DT * fv0.x, SIGMA), 256.f - SIGMA);
      float mu1 = fminf(fmaxf(spy + DT * fv0.w, SIGMA), 256.f - SIGMA);
      float sz0 = fminf(fmaxf(0.5f - fabsf(px - mu0) + SIGMA, 0.f), 1.f);
      float sz1 = fminf(fmaxf(0.5f - fabsf(py - mu1) + SIGMA, 0.f), 1.f);
      float na0 = av.x * (sz0 * sz1 * INV4S2);
      // c = 1
      mu0 = fminf(fmaxf(spx + DT * fv0.y, SIGMA), 256.f - SIGMA);
      mu1 = fminf(fmaxf(spy + DT * fv1.x, SIGMA), 256.f - SIGMA);
      sz0 = fminf(fmaxf(0.5f - fabsf(px - mu0) + SIGMA, 0.f), 1.f);
      sz1 = fminf(fmaxf(0.5f - fabsf(py - mu1) + SIGMA, 0.f), 1.f);
      float na1 = av.y * (sz0 * sz1 * INV4S2);
      // c = 2
      mu0 = fminf(fmaxf(spx + DT * fv0.z, SIGMA), 256.f - SIGMA);
      mu1 = fminf(fmaxf(spy + DT * fv1.y, SIGMA), 256.f - SIGMA);
      sz0 = fminf(fmaxf(0.5f - fabsf(px - mu0) + SIGMA, 0.f), 1.f);
      sz1 = fminf(fmaxf(0.5f - fabsf(py - mu1) + SIGMA, 0.f), 1.f);
      float na2 = av.z * (sz0 * sz1 * INV4S2);

      const float e = __expf(na0 + na1 + na2) - 1.0f;
      accA0 += na0; accA1 += na1; accA2 += na2;
      esum += e;
      const float4 p0 = lP[0][lc];
      const float4 p1 = lP[1][lc];
      const float4 p2 = lP[2][lc];
      const float4 p3 = lP[3][lc];
      accP[0]  += p0.x * e; accP[1]  += p0.y * e; accP[2]  += p0.z * e; accP[3]  += p0.w * e;
      accP[4]  += p1.x * e; accP[5]  += p1.y * e; accP[6]  += p1.z * e; accP[7]  += p1.w * e;
      accP[8]  += p2.x * e; accP[9]  += p2.y * e; accP[10] += p2.z * e; accP[11] += p2.w * e;
      accP[12] += p3.x * e; accP[13] += p3.y * e; accP[14] += p3.z * e;
    }
  }

  const int b = x * 256 + y;
  outA[b * NC + 0] = accA0;
  outA[b * NC + 1] = accA1;
  outA[b * NC + 2] = accA2;
  const float inv = 1.0f / (esum + 1e-10f);
#pragma unroll
  for (int k = 0; k < NK; ++k) outP[b * NK + k] = accP[k] * inv;
}

extern "C" void kernel_launch(void* const* d_in, const int* in_sizes, int n_in,
                              void* d_out, int out_size, void* d_ws, size_t ws_size,
                              hipStream_t stream) {
  const float* A   = (const float*)d_in[0];
  const float* P   = (const float*)d_in[1];
  const float* fKr = (const float*)d_in[2];
  const float* fKi = (const float*)d_in[3];
  const float* m   = (const float*)d_in[4];
  const float* s   = (const float*)d_in[5];

  float* ws = (float*)d_ws;
  float2* RF   = (float2*)ws;                  // 3 * 256 * 136 complex
  float2* T2   = RF + NC * 256 * RW;           // 15 * 256 * 136 complex
  float*  Ucol = (float*)(T2 + NK * 256 * RW); // 3 * 65536 float

  float* outA = (float*)d_out;
  float* outP = outA + NC * XY;

  k_rowfft<<<NC * 64, 256, 0, stream>>>(A, RF);
  k_colfft<<<NK * 17, 512, 0, stream>>>(fKr, fKi, RF, T2);
  k_irowfft_growth<<<NC * 256, 320, 0, stream>>>(T2, P, m, s, Ucol);
  k_flow_reint<<<256, 256, 0, stream>>>(A, P, Ucol, outA, outP);
}